// Round 6
// baseline (268.501 us; speedup 1.0000x reference)
//
#include <hip/hip_runtime.h>

// Workspace layout (float offsets)
#define WS_M2 0          // 16384 floats  (512 x 32)
#define WS_N2 16384      // 2048  floats  (64 x 32)
#define WS_WT 18432      // 131072 floats (32 x 4096), W transposed: Wt[r*4096+o]
#define WS_Z  149504     // 32768 floats  (1024 x 32)

typedef unsigned int u32;
typedef __attribute__((address_space(3))) u32* lds_u32p;
typedef const __attribute__((address_space(1))) u32* glb_u32p;

// async 16B/lane global->LDS copy (wave instr: lds dst = uniform base + lane*16)
__device__ __forceinline__ void async_cp16(const float* g, float* l) {
    __builtin_amdgcn_global_load_lds((glb_u32p)g, (lds_u32p)l, 16, 0, 0);
}

// ---------------------------------------------------------------------------
// Kernel A: collapse TT factor chains into small dense matrices.
// ---------------------------------------------------------------------------
__global__ __launch_bounds__(256) void precompute_kernel(
    const float* __restrict__ f0, const float* __restrict__ f1,
    const float* __restrict__ f2, const float* __restrict__ f3,
    const float* __restrict__ f4, const float* __restrict__ g0,
    const float* __restrict__ g1, const float* __restrict__ g2,
    float* __restrict__ ws)
{
    __shared__ float sA[8192];
    const int t = threadIdx.x;
    const int blk = blockIdx.x;
    if (blk < 8) {
        for (int i = t; i < 2048; i += 256) {
            int a01 = i >> 5, r2 = i & 31;
            int a0 = a01 >> 3, a1 = a01 & 7;
            float s = 0.f;
            #pragma unroll
            for (int r1 = 0; r1 < 32; ++r1)
                s += f0[a0*32 + r1] * f1[r1*256 + a1*32 + r2];
            sA[i] = s;
        }
        __syncthreads();
        for (int i = t; i < 2048; i += 256) {
            int a012 = blk*64 + (i >> 5), r3 = i & 31;
            int a01 = a012 >> 3, a2 = a012 & 7;
            float s = 0.f;
            #pragma unroll
            for (int r2 = 0; r2 < 32; ++r2)
                s += sA[a01*32 + r2] * f2[r2*256 + a2*32 + r3];
            ws[WS_M2 + a012*32 + r3] = s;
        }
    } else if (blk == 8) {
        for (int i = t; i < 2048; i += 256) {
            int a34 = i >> 5, s2 = i & 31;
            int a3 = a34 >> 3, a4 = a34 & 7;
            float s = 0.f;
            #pragma unroll
            for (int s1 = 0; s1 < 32; ++s1)
                s += f3[a3*32 + s1] * f4[s1*256 + a4*32 + s2];
            ws[WS_N2 + i] = s;
        }
    } else {
        const int j = blk - 9;   // 0..31, o-slice
        for (int i = t; i < 8192; i += 256) {
            int o01 = i >> 5, q = i & 31;
            int o0 = o01 >> 4, o1 = o01 & 15;
            float s = 0.f;
            #pragma unroll
            for (int p = 0; p < 32; ++p)
                s += g0[o0*32 + p] * g1[p*512 + o1*32 + q];
            sA[i] = s;
        }
        __syncthreads();
        for (int i = t; i < 4096; i += 256) {
            int o = j*128 + (i >> 5);
            int r = i & 31;
            int o01 = o >> 4, o2 = o & 15;
            float s = 0.f;
            #pragma unroll
            for (int q = 0; q < 32; ++q)
                s += sA[o01*32 + q] * g2[q*512 + o2*32 + r];
            ws[WS_WT + r*4096 + o] = s;
        }
    }
}

// ---------------------------------------------------------------------------
// Kernel B: one block per batch element.
//   phase 1: T3[m,r] = sum_k x[b,k,m]*M2[k,r]  (m=64,k=512,r=32)
//     8m x 8r register tile (64 acc): 4 ds_read_b128 -> 64 FMA (16 FMA/instr).
//     k split 8-way (slice = t>>5); 32-k chunks double-buffered in LDS via
//     async global_load_lds(16B); ONE barrier per chunk; loads for chunk c+1
//     issued before computing chunk c (latency overlapped, un-sinkable).
//   Partial-tile reduce over 8 slices in two r-half passes (LDS reuse),
//   then phase 3 (T5) and phase 4 (z).
// LDS: 14336 floats = 56 KB -> 2 blocks/CU.
// LDS float map:
//   STG0: X@0(2048) M@2048(1024) | STG1: X@3072 M@5120(1024)  [k-loop only]
//   P:    @6144 + q*1024, q=0..7                               [reduce]
//   T3t:  @0 (32 x pitch68)   N2:@2176(2048)  T5:@4224(1024)  spart:@5248
// ---------------------------------------------------------------------------
__global__ __launch_bounds__(256, 2) void main_kernel(
    const float* __restrict__ x, const float* __restrict__ core,
    const float* __restrict__ ws, float* __restrict__ zout)
{
    __shared__ float buf[14336];
    const int t = threadIdx.x;
    const int b = blockIdx.x;
    const int lane = t & 63;
    const int w = t >> 6;          // wave 0..3
    const int s = t >> 5;          // k-slice 0..7
    const int u = t & 31;
    const int mb = u & 7;          // m-block (8 m each)
    const int rb = u >> 3;         // r-block (8 r each)

    const float* __restrict__ xb = x + (size_t)b * 32768;
    const float* __restrict__ m2 = ws + WS_M2;

    float acc[8][8];
    #pragma unroll
    for (int i = 0; i < 8; ++i)
        #pragma unroll
        for (int j = 0; j < 8; ++j) acc[i][j] = 0.f;

    // ---- prologue: stage chunk 0 into STG0
    {
        const float* xs = xb;                   // chunk 0: 2048 floats
        async_cp16(xs + w*512       + lane*4, buf +        w*512);
        async_cp16(xs + w*512 + 256 + lane*4, buf +        w*512 + 256);
        async_cp16(m2 + w*256       + lane*4, buf + 2048 + w*256);
    }
    __syncthreads();

    // ---- k-loop: 16 chunks x 32 k
    for (int c = 0; c < 16; ++c) {
        const int bb = c & 1;
        // issue async staging for chunk c+1 into the other buffer
        if (c + 1 < 16) {
            const int nb = bb ^ 1;
            const float* xs = xb + (c + 1) * 2048;
            const float* ms = m2 + (c + 1) * 1024;
            async_cp16(xs + w*512       + lane*4, buf + nb*3072 +        w*512);
            async_cp16(xs + w*512 + 256 + lane*4, buf + nb*3072 +        w*512 + 256);
            async_cp16(ms + w*256       + lane*4, buf + nb*3072 + 2048 + w*256);
        }
        const float* X = buf + bb*3072;
        const float* M = buf + bb*3072 + 2048;
        #pragma unroll
        for (int kk = 0; kk < 4; ++kk) {
            const int k = s*4 + kk;
            float4 xa = *(const float4*)&X[k*64 + mb*8];
            float4 xc = *(const float4*)&X[k*64 + mb*8 + 4];
            float4 wa = *(const float4*)&M[k*32 + rb*8];
            float4 wb = *(const float4*)&M[k*32 + rb*8 + 4];
            const float xm[8] = {xa.x,xa.y,xa.z,xa.w, xc.x,xc.y,xc.z,xc.w};
            const float wv[8] = {wa.x,wa.y,wa.z,wa.w, wb.x,wb.y,wb.z,wb.w};
            #pragma unroll
            for (int i = 0; i < 8; ++i)
                #pragma unroll
                for (int j = 0; j < 8; ++j)
                    acc[i][j] += xm[i] * wv[j];
        }
        __syncthreads();   // drains c+1 staging (vmcnt) + releases buffer bb
    }

    // prefetch N2 into registers (store to LDS later; latency under reduce)
    const float4* n24 = (const float4*)(ws + WS_N2);
    float4 n0 = n24[t*2];
    float4 n1 = n24[t*2 + 1];

    // ---- reduce 8 partial tiles in two r-half passes -> T3t[r][m] pitch 68 @0
    #pragma unroll
    for (int p = 0; p < 2; ++p) {
        // dump this r-half of acc into P_s  (layout: i*128 + u*4 + jj)
        #pragma unroll
        for (int i = 0; i < 8; ++i) {
            float4 v = {acc[i][p*4+0], acc[i][p*4+1], acc[i][p*4+2], acc[i][p*4+3]};
            *(float4*)&buf[6144 + s*1024 + i*128 + u*4] = v;
        }
        if (p == 1) {   // N2 -> LDS, covered by the same barrier
            *(float4*)&buf[2176 + t*8]     = n0;
            *(float4*)&buf[2176 + t*8 + 4] = n1;
        }
        __syncthreads();
        // reduce: thread handles (rbb, jj, m-run of 4)
        {
            const int rbb = t >> 6, jj = (t >> 4) & 3, mq = t & 15;
            const int mbb = mq >> 1, i0 = (mq & 1) * 4;
            float sum0=0.f, sum1=0.f, sum2=0.f, sum3=0.f;
            #pragma unroll
            for (int q = 0; q < 8; ++q) {
                const float* P = &buf[6144 + q*1024 + (rbb*8 + mbb)*4 + jj];
                sum0 += P[(i0+0)*128]; sum1 += P[(i0+1)*128];
                sum2 += P[(i0+2)*128]; sum3 += P[(i0+3)*128];
            }
            const int r = rbb*8 + p*4 + jj;
            float4 v = {sum0, sum1, sum2, sum3};
            *(float4*)&buf[r*68 + mq*4] = v;
        }
        __syncthreads();
    }

    // ---- phase 3: T5[r3,s2] = sum_m T3t[r3,m] * N2[m,s2] -> @4224
    {
        const int r3  = t >> 3;
        const int s2b = (t & 7) * 4;
        float a0=0.f, a1=0.f, a2=0.f, a3=0.f;
        #pragma unroll 8
        for (int m = 0; m < 64; ++m) {
            float av = buf[r3*68 + m];
            const float* n = &buf[2176 + m*32 + s2b];
            a0 += av*n[0]; a1 += av*n[1]; a2 += av*n[2]; a3 += av*n[3];
        }
        float* d = &buf[4224 + r3*32 + s2b];
        d[0]=a0; d[1]=a1; d[2]=a2; d[3]=a3;
    }
    __syncthreads();

    // ---- phase 4: z[ro] = sum_k T5[k] * core[k,ro]
    {
        const int ro2 = t & 15;
        const int kc  = t >> 4;
        const float2* core2 = (const float2*)core;
        float s0 = 0.f, s1 = 0.f;
        const int k0 = kc * 64;
        for (int k = k0; k < k0 + 64; ++k) {
            float tv = buf[4224 + k];
            float2 cv = core2[k*16 + ro2];
            s0 += tv*cv.x; s1 += tv*cv.y;
        }
        buf[5248 + kc*32 + ro2*2 + 0] = s0;
        buf[5248 + kc*32 + ro2*2 + 1] = s1;
    }
    __syncthreads();
    if (t < 32) {
        float s2 = 0.f;
        #pragma unroll
        for (int kc = 0; kc < 16; ++kc) s2 += buf[5248 + kc*32 + t];
        zout[b*32 + t] = s2;
    }
}

// ---------------------------------------------------------------------------
// Kernel C: out[b,o] = sum_r z[b,r]*Wt[r,o] + bias[o]
// ---------------------------------------------------------------------------
__global__ __launch_bounds__(256) void out_kernel(
    const float* __restrict__ ws, const float* __restrict__ bias,
    float* __restrict__ out)
{
    __shared__ float sW[8192];   // Wt tile [32][256]
    __shared__ float sZt[2176];  // z tile transposed [32 ro][68]
    __shared__ float sB[256];
    const int t  = threadIdx.x;
    const int bt = blockIdx.x;
    const int ot = blockIdx.y;

    {
        const float4* wt4 = (const float4*)(ws + WS_WT);
        float4* d = (float4*)sW;
        #pragma unroll
        for (int i = 0; i < 8; ++i) {
            int idx = i*256 + t;
            int ro = idx >> 6, oc = idx & 63;
            d[idx] = wt4[ro*1024 + ot*64 + oc];
        }
    }
    {
        const float4* z4 = (const float4*)(ws + WS_Z) + bt*512;
        #pragma unroll
        for (int i = 0; i < 2; ++i) {
            int idx = i*256 + t;
            int bl = idx >> 3, r4 = idx & 7;
            float4 v = z4[idx];
            sZt[(r4*4 + 0)*68 + bl] = v.x;
            sZt[(r4*4 + 1)*68 + bl] = v.y;
            sZt[(r4*4 + 2)*68 + bl] = v.z;
            sZt[(r4*4 + 3)*68 + bl] = v.w;
        }
    }
    if (t < 64) {
        const float4* b4 = (const float4*)bias + ot*64;
        ((float4*)sB)[t] = b4[t];
    }
    __syncthreads();

    const int oc = t & 63;
    const int bg = t >> 6;
    const float4* sW4 = (const float4*)sW;
    const float4 bv = ((const float4*)sB)[oc];
    float4* out4 = (float4*)out;

    for (int bi = 0; bi < 16; bi += 4) {
        const int bl = bg*16 + bi;
        float4 a0 = bv, a1 = bv, a2 = bv, a3 = bv;
        #pragma unroll
        for (int ro = 0; ro < 32; ++ro) {
            float4 w = sW4[ro*64 + oc];
            float4 z = *(const float4*)&sZt[ro*68 + bl];
            a0.x += z.x*w.x; a0.y += z.x*w.y; a0.z += z.x*w.z; a0.w += z.x*w.w;
            a1.x += z.y*w.x; a1.y += z.y*w.y; a1.z += z.y*w.z; a1.w += z.y*w.w;
            a2.x += z.z*w.x; a2.y += z.z*w.y; a2.z += z.z*w.z; a2.w += z.z*w.w;
            a3.x += z.w*w.x; a3.y += z.w*w.y; a3.z += z.w*w.z; a3.w += z.w*w.w;
        }
        const size_t obase = (size_t)(bt*64 + bl) * 1024 + ot*64 + oc;
        out4[obase + 0*1024] = a0;
        out4[obase + 1*1024] = a1;
        out4[obase + 2*1024] = a2;
        out4[obase + 3*1024] = a3;
    }
}

extern "C" void kernel_launch(void* const* d_in, const int* in_sizes, int n_in,
                              void* d_out, int out_size, void* d_ws, size_t ws_size,
                              hipStream_t stream)
{
    const float* x    = (const float*)d_in[0];
    const float* f0   = (const float*)d_in[1];
    const float* f1   = (const float*)d_in[2];
    const float* f2   = (const float*)d_in[3];
    const float* f3   = (const float*)d_in[4];
    const float* f4   = (const float*)d_in[5];
    const float* core = (const float*)d_in[6];
    const float* g0   = (const float*)d_in[7];
    const float* g1   = (const float*)d_in[8];
    const float* g2   = (const float*)d_in[9];
    const float* bias = (const float*)d_in[10];
    float* ws  = (float*)d_ws;
    float* out = (float*)d_out;

    precompute_kernel<<<41, 256, 0, stream>>>(f0, f1, f2, f3, f4, g0, g1, g2, ws);
    main_kernel<<<1024, 256, 0, stream>>>(x, core, ws, ws + WS_Z);
    out_kernel<<<dim3(16, 16), 256, 0, stream>>>(ws, bias, out);
}